// Round 8
// baseline (326.322 us; speedup 1.0000x reference)
//
#include <hip/hip_runtime.h>
#include <hip/hip_cooperative_groups.h>

namespace cg = cooperative_groups;

typedef unsigned short u16;
typedef short bf16x8 __attribute__((ext_vector_type(8)));
typedef float f32x4 __attribute__((ext_vector_type(4)));

__device__ __forceinline__ u16 f2bf(float f) {
    unsigned u = __float_as_uint(f);
    return (u16)((u + 0x7fffu + ((u >> 16) & 1u)) >> 16);
}
__device__ __forceinline__ float exp2_hw(float x) {
    float r;
    asm("v_exp_f32 %0, %1" : "=v"(r) : "v"(x));
    return r;
}
template <int CTRL>
__device__ __forceinline__ float dpp_add(float p) {
    int t = __builtin_amdgcn_update_dpp(0, __float_as_int(p), CTRL, 0xf, 0xf, true);
    return p + __int_as_float(t);
}
__device__ __forceinline__ void gload_lds16(const u16* g, u16* lds) {
    __builtin_amdgcn_global_load_lds((const __attribute__((address_space(1))) void*)g,
                                     (__attribute__((address_space(3))) void*)lds, 16, 0, 0);
}

struct MegaP {
    const float* x; const int* ei;
    const float *W1l, *b1l, *W1r, *b1r, *att1, *bias1;
    const float *W2l, *b2l, *W2r, *b2r, *att2, *bias2;
    const float *Wp1, *bp1, *Wp2, *bp2;
    u16 *Abuf, *XLR, *WB1, *WB2, *Wpt;
    float *bc1, *bc2, *bpf;
    int *cnt, *rowptr, *cursor, *csr, *bsums;
    float* outF;
    int N, E, Mpad, Mt;
};

// ---------------- shared device phase functions ----------------

template <bool AF32, int BN, bool F32OUT>
__device__ __forceinline__ void gemm_phase(const void* __restrict__ Av, const u16* __restrict__ Bt,
                                           const float* __restrict__ bias, void* __restrict__ out,
                                           int M, int Nout, int Mt, u16* As, u16* Bs) {
    constexpr int K = 256;
    constexpr int NRF = BN / 64;
    const int tid = threadIdx.x;
    const int l = tid & 63;
    const int w = tid >> 6;
    const int wm = w >> 2, wn = w & 3;
    const int lrow = l & 15, lk = l >> 4;
    const int wbase = tid & ~63;
    const int ct = Nout / BN;
    const int ntile = Mt * ct;

    for (int t = blockIdx.x; t < ntile; t += gridDim.x) {
        const int bm = t / ct, bn = t % ct;
        __syncthreads();  // prior tile's (or prior phase's) LDS reads done

#pragma unroll
        for (int it = 0; it < BN / 16; ++it) {  // stage B panel (XOR chunk swizzle)
            int c = it * 512 + tid;
            int col = c >> 5, kc = c & 31;
            bf16x8 v = *(const bf16x8*)(Bt + (size_t)(bn * BN + col) * K + kc * 8);
            *(bf16x8*)(Bs + col * K + ((kc ^ (col & 7)) * 8)) = v;
        }

        auto stageA = [&](int ks) {
            if (AF32) {
                const float* A32 = (const float*)Av;
#pragma unroll
                for (int it = 0; it < 2; ++it) {
                    int c = it * 512 + tid;
                    int row = c >> 3, seg = c & 7;
                    int grow = bm * 128 + row;
                    if (grow > M - 1) grow = M - 1;
                    const float* sp = A32 + (size_t)grow * K + ks * 64 + seg * 8;
                    float4 v0 = *(const float4*)sp;
                    float4 v1 = *(const float4*)(sp + 4);
                    bf16x8 pk;
                    pk[0] = (short)f2bf(v0.x); pk[1] = (short)f2bf(v0.y);
                    pk[2] = (short)f2bf(v0.z); pk[3] = (short)f2bf(v0.w);
                    pk[4] = (short)f2bf(v1.x); pk[5] = (short)f2bf(v1.y);
                    pk[6] = (short)f2bf(v1.z); pk[7] = (short)f2bf(v1.w);
                    *(bf16x8*)(As + row * 64 + ((seg ^ (row & 7)) * 8)) = pk;
                }
            } else {
                const u16* Abf = (const u16*)Av;
#pragma unroll
                for (int it = 0; it < 2; ++it) {
                    int c = it * 512 + tid;
                    int row = c >> 3, seg = c & 7;
                    int ssrc = seg ^ (row & 7);
                    gload_lds16(Abf + (size_t)(bm * 128 + row) * K + ks * 64 + ssrc * 8,
                                As + (size_t)(it * 512 + wbase) * 8);
                }
            }
        };

        f32x4 acc[4][NRF];
#pragma unroll
        for (int m = 0; m < 4; ++m)
#pragma unroll
            for (int n = 0; n < NRF; ++n) acc[m][n] = (f32x4){0.f, 0.f, 0.f, 0.f};

        stageA(0);
        __syncthreads();

        for (int ks = 0; ks < 4; ++ks) {
#pragma unroll
            for (int h = 0; h < 2; ++h) {
                bf16x8 av[4], bv[NRF];
#pragma unroll
                for (int m = 0; m < 4; ++m) {
                    int row = wm * 64 + m * 16 + lrow;
                    int seg = ((h * 4 + lk) ^ (row & 7));
                    av[m] = *(const bf16x8*)(As + row * 64 + seg * 8);
                }
#pragma unroll
                for (int n = 0; n < NRF; ++n) {
                    int col = wn * (NRF * 16) + n * 16 + lrow;
                    int kc = ks * 8 + h * 4 + lk;
                    bv[n] = *(const bf16x8*)(Bs + col * K + ((kc ^ (col & 7)) * 8));
                }
#pragma unroll
                for (int m = 0; m < 4; ++m)
#pragma unroll
                    for (int n = 0; n < NRF; ++n)
                        acc[m][n] = __builtin_amdgcn_mfma_f32_16x16x32_bf16(av[m], bv[n], acc[m][n], 0, 0, 0);
            }
            if (ks < 3) {
                __syncthreads();
                stageA(ks + 1);
                __syncthreads();
            }
        }

        float bl[NRF];
#pragma unroll
        for (int n = 0; n < NRF; ++n) bl[n] = bias[bn * BN + wn * (NRF * 16) + n * 16 + lrow];

#pragma unroll
        for (int m = 0; m < 4; ++m) {
            int grow = bm * 128 + wm * 64 + m * 16 + lk * 4;
#pragma unroll
            for (int j = 0; j < 4; ++j) {
                if (grow + j < M) {
#pragma unroll
                    for (int n = 0; n < NRF; ++n) {
                        int col = bn * BN + wn * (NRF * 16) + n * 16 + lrow;
                        float v = acc[m][n][j] + bl[n];
                        if (F32OUT)
                            ((float*)out)[(size_t)(grow + j) * Nout + col] = v;
                        else
                            ((u16*)out)[(size_t)(grow + j) * Nout + col] = f2bf(v);
                    }
                }
            }
        }
    }
}

__device__ __forceinline__ void edge_phase(const int* __restrict__ rowptr, const int* __restrict__ csr,
                                           const u16* __restrict__ XLR, const float* __restrict__ att,
                                           const float* __restrict__ bias, u16* __restrict__ H, int N) {
    const int l = threadIdx.x & 63;
    const int nwave = gridDim.x << 3;
    const float LOG2E = 1.4426950408889634f;
    float4 a4 = *(const float4*)(att + l * 4);
    a4.x *= LOG2E; a4.y *= LOG2E; a4.z *= LOG2E; a4.w *= LOG2E;
    float4 bb = *(const float4*)(bias + l * 4);
    const char* Xb = (const char*)XLR;
    const int lofs = l << 3;

    for (int wid0 = (blockIdx.x << 3) + (threadIdx.x >> 6); wid0 < N; wid0 += nwave) {
        const int wid = __builtin_amdgcn_readfirstlane(wid0);
        uint2 xr = *(const uint2*)(Xb + ((size_t)wid << 10) + 512 + lofs);
        float r0 = __uint_as_float(xr.x << 16), r1 = __uint_as_float(xr.x & 0xffff0000u);
        float r2 = __uint_as_float(xr.y << 16), r3 = __uint_as_float(xr.y & 0xffff0000u);

        int beg = rowptr[wid], end = rowptr[wid + 1];
        float s = 0.f, o0 = 0.f, o1 = 0.f, o2 = 0.f, o3 = 0.f;

        auto edge1 = [&](uint2 wv) {
            float c0 = __uint_as_float(wv.x << 16), c1 = __uint_as_float(wv.x & 0xffff0000u);
            float c2 = __uint_as_float(wv.y << 16), c3 = __uint_as_float(wv.y & 0xffff0000u);
            float t0 = c0 + r0, t1 = c1 + r1, t2 = c2 + r2, t3 = c3 + r3;
            t0 = fmaf(-0.8f, fminf(t0, 0.f), t0);
            t1 = fmaf(-0.8f, fminf(t1, 0.f), t1);
            t2 = fmaf(-0.8f, fminf(t2, 0.f), t2);
            t3 = fmaf(-0.8f, fminf(t3, 0.f), t3);
            float p = t0 * a4.x; p = fmaf(t1, a4.y, p); p = fmaf(t2, a4.z, p); p = fmaf(t3, a4.w, p);
            p = dpp_add<0xB1>(p);
            p = dpp_add<0x4E>(p);
            p = dpp_add<0x141>(p);
            p = dpp_add<0x140>(p);
            float e = exp2_hw(p);
            s += e;
            o0 = fmaf(e, c0, o0); o1 = fmaf(e, c1, o1);
            o2 = fmaf(e, c2, o2); o3 = fmaf(e, c3, o3);
        };

        int i = beg;
        for (; i + 4 <= end; i += 4) {
            int u0 = __builtin_amdgcn_readfirstlane(csr[i]);
            int u1 = __builtin_amdgcn_readfirstlane(csr[i + 1]);
            int u2 = __builtin_amdgcn_readfirstlane(csr[i + 2]);
            int u3 = __builtin_amdgcn_readfirstlane(csr[i + 3]);
            uint2 w0 = *(const uint2*)(Xb + ((size_t)u0 << 10) + lofs);
            uint2 w1 = *(const uint2*)(Xb + ((size_t)u1 << 10) + lofs);
            uint2 w2 = *(const uint2*)(Xb + ((size_t)u2 << 10) + lofs);
            uint2 w3 = *(const uint2*)(Xb + ((size_t)u3 << 10) + lofs);
            edge1(w0); edge1(w1); edge1(w2); edge1(w3);
        }
        for (; i < end; ++i) {
            int u0 = __builtin_amdgcn_readfirstlane(csr[i]);
            uint2 w0 = *(const uint2*)(Xb + ((size_t)u0 << 10) + lofs);
            edge1(w0);
        }

        float inv = 1.f / s;
        o0 = fmaxf(fmaf(o0, inv, bb.x), 0.f);
        o1 = fmaxf(fmaf(o1, inv, bb.y), 0.f);
        o2 = fmaxf(fmaf(o2, inv, bb.z), 0.f);
        o3 = fmaxf(fmaf(o3, inv, bb.w), 0.f);
        ushort4 w4 = {f2bf(o0), f2bf(o1), f2bf(o2), f2bf(o3)};
        *(ushort4*)(H + ((size_t)wid << 8) + l * 4) = w4;
    }
}

// ---------------- mega kernel (cooperative path) ----------------
__shared__ __align__(16) u16 LDSbuf[40960];  // 80KB: As [0,8192), Bs [8192,40960)

__global__ __launch_bounds__(512, 4) void k_mega(MegaP P) {
    cg::grid_group gg = cg::this_grid();
    const int bid = blockIdx.x, tid = threadIdx.x;
    const int gthr = bid * 512 + tid;
    const int nthr = gridDim.x * 512;
    const int N = P.N, E = P.E, EP = E + N;

    // phase 0: zero + prep
    for (int i = gthr; i < N; i += nthr) P.cnt[i] = 0;
    {
        int pad = (P.Mpad - N) * 256;
        for (int i = gthr; i < pad; i += nthr) P.Abuf[(size_t)N * 256 + i] = 0;
    }
    for (int v = gthr; v < 262144; v += nthr) {
        int m = v >> 16, k = (v >> 8) & 255, n = v & 255;
        const float* W = (m == 0) ? P.W1l : (m == 1) ? P.W1r : (m == 2) ? P.W2l : P.W2r;
        u16* dst = (m < 2) ? P.WB1 : P.WB2;
        dst[(size_t)((m & 1) * 256 + n) * 256 + k] = f2bf(W[(size_t)k * 256 + n]);
    }
    for (int v = gthr; v < 64 * 256; v += nthr) {
        int j = v >> 8, i = v & 255;
        float a = 0.f;
        for (int k = 0; k < 64; ++k) a += P.Wp1[i * 64 + k] * P.Wp2[k * 64 + j];
        P.Wpt[j * 256 + i] = f2bf(a);
        if (i == 0) {
            float bb = P.bp2[j];
            for (int k = 0; k < 64; ++k) bb += P.bp1[k] * P.Wp2[k * 64 + j];
            P.bpf[j] = bb;
        }
    }
    for (int v = gthr; v < 1024; v += nthr) {
        int m = v >> 8, i = v & 255;
        const float* sp = (m == 0) ? P.b1l : (m == 1) ? P.b1r : (m == 2) ? P.b2l : P.b2r;
        float* d = (m < 2) ? P.bc1 : P.bc2;
        d[(m & 1) * 256 + i] = sp[i];
    }
    gg.sync();

    // phase 1: degree count
    for (int e = gthr; e < EP; e += nthr) {
        int dst = (e < E) ? P.ei[E + e] : (e - E);
        atomicAdd(P.cnt + dst, 1);
    }
    gg.sync();

    // phase 2: exclusive scan (block 0)
    if (bid == 0) {
        int* sd = (int*)LDSbuf;
        const int CH = (N + 511) / 512;
        const int s0 = tid * CH;
        int lsum = 0;
        for (int i = 0; i < CH; ++i) {
            int idx = s0 + i;
            lsum += (idx < N) ? P.cnt[idx] : 0;
        }
        sd[tid] = lsum;
        __syncthreads();
        for (int ofs = 1; ofs < 512; ofs <<= 1) {
            int t = (tid >= ofs) ? sd[tid - ofs] : 0;
            __syncthreads();
            sd[tid] += t;
            __syncthreads();
        }
        int run = sd[tid] - lsum;
        for (int i = 0; i < CH; ++i) {
            int idx = s0 + i;
            if (idx < N) {
                P.rowptr[idx] = run;
                P.cursor[idx] = run;
                run += P.cnt[idx];
            }
        }
        if (tid == 0) P.rowptr[N] = EP;
        __syncthreads();
    }
    gg.sync();

    // phase 3: scatter
    for (int e = gthr; e < EP; e += nthr) {
        int src, dst;
        if (e < E) { src = P.ei[e]; dst = P.ei[E + e]; }
        else       { src = e - E; dst = e - E; }
        int p = atomicAdd(P.cursor + dst, 1);
        P.csr[p] = src;
    }
    gg.sync();

    u16* As = LDSbuf;
    u16* Bs = LDSbuf + 8192;

    gemm_phase<true, 128, false>(P.x, P.WB1, P.bc1, P.XLR, N, 512, P.Mt, As, Bs);
    gg.sync();
    edge_phase(P.rowptr, P.csr, P.XLR, P.att1, P.bias1, P.Abuf, N);
    gg.sync();
    gemm_phase<false, 128, false>(P.Abuf, P.WB2, P.bc2, P.XLR, N, 512, P.Mt, As, Bs);
    gg.sync();
    edge_phase(P.rowptr, P.csr, P.XLR, P.att2, P.bias2, P.Abuf, N);
    gg.sync();
    gemm_phase<false, 64, true>(P.Abuf, P.Wpt, P.bpf, P.outF, N, 64, P.Mt, As, Bs);
}

// ---------------- fallback multi-kernel path ----------------

__global__ __launch_bounds__(256) void k_prep(MegaP P) {
    const int N = P.N, E = P.E, EP = E + N;
    const int nCnt = (EP + 255) / 256;
    const int c0 = 1024, c1 = c0 + 64, c2 = c1 + nCnt;
    int b = blockIdx.x;
    int tid = threadIdx.x;
    if (b < c0) {
        int n = b & 255, m = b >> 8;
        const float* W = (m == 0) ? P.W1l : (m == 1) ? P.W1r : (m == 2) ? P.W2l : P.W2r;
        u16* dst = (m < 2) ? P.WB1 : P.WB2;
        dst[(size_t)((m & 1) * 256 + n) * 256 + tid] = f2bf(W[(size_t)tid * 256 + n]);
    } else if (b < c1) {
        int j = b - c0;
        float a = 0.f;
        for (int k = 0; k < 64; ++k) a += P.Wp1[tid * 64 + k] * P.Wp2[k * 64 + j];
        P.Wpt[j * 256 + tid] = f2bf(a);
        if (tid == 0) {
            float bb = P.bp2[j];
            for (int k = 0; k < 64; ++k) bb += P.bp1[k] * P.Wp2[k * 64 + j];
            P.bpf[j] = bb;
        }
    } else if (b < c2) {
        int e = (b - c1) * 256 + tid;
        if (e < EP) {
            int dst = (e < E) ? P.ei[E + e] : (e - E);
            atomicAdd(P.cnt + dst, 1);
        }
    } else {
        int m = b - c2;
        const float* s = (m == 0) ? P.b1l : (m == 1) ? P.b1r : (m == 2) ? P.b2l : P.b2r;
        float* d = (m < 2) ? P.bc1 : P.bc2;
        d[(m & 1) * 256 + tid] = s[tid];
    }
}

__global__ __launch_bounds__(256) void k_scan_block(const int* __restrict__ cnt,
                                                    int* __restrict__ rowptr,
                                                    int* __restrict__ bsums, int N) {
    __shared__ int sd[256];
    int tid = threadIdx.x;
    int base = blockIdx.x * 1024 + tid * 4;
    int v0 = (base + 0 < N) ? cnt[base + 0] : 0;
    int v1 = (base + 1 < N) ? cnt[base + 1] : 0;
    int v2 = (base + 2 < N) ? cnt[base + 2] : 0;
    int v3 = (base + 3 < N) ? cnt[base + 3] : 0;
    int ts = v0 + v1 + v2 + v3;
    sd[tid] = ts;
    __syncthreads();
    for (int ofs = 1; ofs < 256; ofs <<= 1) {
        int t = (tid >= ofs) ? sd[tid - ofs] : 0;
        __syncthreads();
        sd[tid] += t;
        __syncthreads();
    }
    int excl = sd[tid] - ts;
    if (base + 0 < N) rowptr[base + 0] = excl;
    if (base + 1 < N) rowptr[base + 1] = excl + v0;
    if (base + 2 < N) rowptr[base + 2] = excl + v0 + v1;
    if (base + 3 < N) rowptr[base + 3] = excl + v0 + v1 + v2;
    if (tid == 255) bsums[blockIdx.x] = sd[255];
}

__global__ void k_scan_bsums(int* __restrict__ bsums, int nb) {
    int l = threadIdx.x;
    int v = (l < nb) ? bsums[l] : 0;
    int x = v;
    for (int ofs = 1; ofs < 64; ofs <<= 1) {
        int t = __shfl_up(x, ofs);
        if (l >= ofs) x += t;
    }
    if (l < nb) bsums[l] = x - v;
}

__global__ __launch_bounds__(256) void k_finalize(int* __restrict__ rowptr,
                                                  const int* __restrict__ bscan,
                                                  int* __restrict__ cursor, int N, int EP) {
    int i = blockIdx.x * 256 + threadIdx.x;
    if (i < N) {
        int v = rowptr[i] + bscan[i >> 10];
        rowptr[i] = v;
        cursor[i] = v;
    } else if (i == N) {
        rowptr[N] = EP;
    }
}

__global__ __launch_bounds__(256) void k_scatter(const int* __restrict__ ei,
                                                 int* __restrict__ cursor,
                                                 int* __restrict__ csr, int E, int N) {
    int e = blockIdx.x * 256 + threadIdx.x;
    if (e < E + N) {
        int src, dst;
        if (e < E) { src = ei[e]; dst = ei[E + e]; }
        else       { src = e - E; dst = e - E; }
        int p = atomicAdd(cursor + dst, 1);
        csr[p] = src;
    }
}

__global__ __launch_bounds__(512) void k_g1(MegaP P) {
    __shared__ __align__(16) u16 As[8192];
    __shared__ __align__(16) u16 Bs[32768];
    gemm_phase<true, 128, false>(P.x, P.WB1, P.bc1, P.XLR, P.N, 512, P.Mt, As, Bs);
}
__global__ __launch_bounds__(512) void k_g2(MegaP P) {
    __shared__ __align__(16) u16 As[8192];
    __shared__ __align__(16) u16 Bs[32768];
    gemm_phase<false, 128, false>(P.Abuf, P.WB2, P.bc2, P.XLR, P.N, 512, P.Mt, As, Bs);
}
__global__ __launch_bounds__(512) void k_gp(MegaP P) {
    __shared__ __align__(16) u16 As[8192];
    __shared__ __align__(16) u16 Bs[32768];
    gemm_phase<false, 64, true>(P.Abuf, P.Wpt, P.bpf, P.outF, P.N, 64, P.Mt, As, Bs);
}
__global__ __launch_bounds__(512) void k_e1(MegaP P) {
    edge_phase(P.rowptr, P.csr, P.XLR, P.att1, P.bias1, P.Abuf, P.N);
}
__global__ __launch_bounds__(512) void k_e2(MegaP P) {
    edge_phase(P.rowptr, P.csr, P.XLR, P.att2, P.bias2, P.Abuf, P.N);
}

// ---------------- launcher ----------------

extern "C" void kernel_launch(void* const* d_in, const int* in_sizes, int n_in,
                              void* d_out, int out_size, void* d_ws, size_t ws_size,
                              hipStream_t stream) {
    MegaP P;
    P.x     = (const float*)d_in[0];
    P.ei    = (const int*)d_in[1];
    P.W1l   = (const float*)d_in[2];  P.b1l  = (const float*)d_in[3];
    P.W1r   = (const float*)d_in[4];  P.b1r  = (const float*)d_in[5];
    P.att1  = (const float*)d_in[6];  P.bias1 = (const float*)d_in[7];
    P.W2l   = (const float*)d_in[8];  P.b2l  = (const float*)d_in[9];
    P.W2r   = (const float*)d_in[10]; P.b2r  = (const float*)d_in[11];
    P.att2  = (const float*)d_in[12]; P.bias2 = (const float*)d_in[13];
    P.Wp1   = (const float*)d_in[14]; P.bp1  = (const float*)d_in[15];
    P.Wp2   = (const float*)d_in[16]; P.bp2  = (const float*)d_in[17];

    const int N = in_sizes[0] / 256;
    const int E = in_sizes[1] / 2;
    const int EP = E + N;
    const int Mpad = ((N + 127) / 128) * 128;

    char* ws = (char*)d_ws;
    size_t o = 0;
    auto alloc = [&](size_t b) { char* p = ws + o; o = (o + b + 255) & ~(size_t)255; return p; };
    P.Abuf   = (u16*)alloc((size_t)Mpad * 256 * 2);
    P.XLR    = (u16*)alloc((size_t)Mpad * 512 * 2);
    P.WB1    = (u16*)alloc(512 * 256 * 2);
    P.WB2    = (u16*)alloc(512 * 256 * 2);
    P.Wpt    = (u16*)alloc(64 * 256 * 2);
    P.bc1    = (float*)alloc(512 * 4);
    P.bc2    = (float*)alloc(512 * 4);
    P.bpf    = (float*)alloc(64 * 4);
    P.cnt    = (int*)alloc((size_t)N * 4);
    P.rowptr = (int*)alloc((size_t)(N + 1) * 4);
    P.cursor = (int*)alloc((size_t)N * 4);
    P.bsums  = (int*)alloc(64 * 4);
    P.csr    = (int*)alloc((size_t)EP * 4);
    P.outF   = (float*)d_out;
    P.N = N; P.E = E; P.Mpad = Mpad; P.Mt = Mpad / 128;

    // ---- decide: cooperative mega-kernel vs multi-kernel fallback ----
    int dev = 0;
    hipGetDevice(&dev);
    int coopOK = 0;
    hipDeviceGetAttribute(&coopOK, hipDeviceAttributeCooperativeLaunch, dev);
    int nCU = 0;
    hipDeviceGetAttribute(&nCU, hipDeviceAttributeMultiprocessorCount, dev);
    int maxB = 0;
    hipOccupancyMaxActiveBlocksPerMultiprocessor(&maxB, k_mega, 512, 0);

    bool launched = false;
    if (coopOK && maxB >= 2 && nCU > 0) {
        int grid = maxB * nCU;
        if (grid > 512) grid = 512;
        void* args[] = { &P };
        hipError_t err = hipLaunchCooperativeKernel((const void*)k_mega, dim3(grid), dim3(512),
                                                    args, 0, stream);
        launched = (err == hipSuccess);
    }
    if (launched) return;

    // ---- fallback: proven multi-kernel sequence (r5 ≈ 316µs) ----
    hipMemsetAsync(P.cnt, 0, (size_t)N * 4, stream);
    if (Mpad > N)
        hipMemsetAsync(P.Abuf + (size_t)N * 256, 0, (size_t)(Mpad - N) * 256 * 2, stream);

    const int nCnt = (EP + 255) / 256;
    k_prep<<<1024 + 64 + nCnt + 4, 256, 0, stream>>>(P);

    int nb = (N + 1023) / 1024;
    k_scan_block<<<nb, 256, 0, stream>>>(P.cnt, P.rowptr, P.bsums, N);
    k_scan_bsums<<<1, 64, 0, stream>>>(P.bsums, nb);
    k_finalize<<<(N + 1 + 255) / 256, 256, 0, stream>>>(P.rowptr, P.bsums, P.cursor, N, EP);
    k_scatter<<<nCnt, 256, 0, stream>>>(P.ei, P.cursor, P.csr, E, N);

    const int egrid = (N + 7) / 8;
    k_g1<<<P.Mt * 4, 512, 0, stream>>>(P);
    k_e1<<<egrid, 512, 0, stream>>>(P);
    k_g2<<<P.Mt * 4, 512, 0, stream>>>(P);
    k_e2<<<egrid, 512, 0, stream>>>(P);
    k_gp<<<P.Mt, 512, 0, stream>>>(P);
}